// Round 3
// baseline (1470.922 us; speedup 1.0000x reference)
//
#include <hip/hip_runtime.h>
#include <stdint.h>

#define B_ 4
#define N_ 256
#define H_ 192
#define H3_ 576
#define F_ 64
#define SH_ 12      // hidden per slice (16 slices)
#define SC_ 36      // 3 gates * SH_
#define MVT_ 144    // 9 col-groups * 16 k-chunks

// ---- workspace layout (32-bit words) ----
// HL/SL rows are 192 tagged u64 elements: (low32 = fp32 bits, high32 = tag = t+1).
#define H0_OFF   0u
#define ZC_OFF   1024u
#define HL_OFF   2048u        // [b][t][192] tagged h_prov, 384 words/row
#define SL_OFF   395264u      // [b][t][192] tagged S rows
#define AN_OFF   788480u      // [b][t][4] u64 ancestor masks
#define TG_OFF   796672u      // [b][t][4] u64 target masks
#define PL_OFF   804864u      // parent lists (u8)
#define PC_OFF   870400u      // parent counts
#define DG_OFF   871424u      // 1/deg
#define G_OFF    872448u      // S@W1b
#define C_OFF    1069056u     // Hprov@W1a + zc
#define CL_OFF   1265664u     // children lists (u8)
#define CC_OFF   1331200u     // children counts

#define AN64 (AN_OFF/2)
#define TG64 (TG_OFF/2)

#define NF_OUT 262144u
#define LL_OUT 327680u

__device__ __forceinline__ float sigm_(float x){ return 1.0f/(1.0f + __expf(-x)); }
__device__ __forceinline__ float tanh_(float x){
  float ax = fabsf(x);
  float e = __expf(-2.0f*ax);
  float t = (1.0f - e)/(1.0f + e);
  return x < 0.0f ? -t : t;
}

// tagged 64-bit publish/poll: single-copy-atomic u64 = (tag<<32)|fp32bits, agent scope (sc1).
__device__ __forceinline__ void stt_(uint32_t* p, float v, uint32_t tag){
  unsigned long long u = ((unsigned long long)tag<<32) | (unsigned long long)__float_as_uint(v);
  __hip_atomic_store((unsigned long long*)p, u, __ATOMIC_RELAXED, __HIP_MEMORY_SCOPE_AGENT);
}
__device__ __forceinline__ unsigned long long ldt_(const uint32_t* p){
  return __hip_atomic_load((const unsigned long long*)p, __ATOMIC_RELAXED, __HIP_MEMORY_SCOPE_AGENT);
}
// poll 12 tagged words (one slice chunk) until all tags match; returns values.
__device__ __forceinline__ void poll12_(const uint32_t* base, uint32_t tag, float out[12]){
  unsigned long long x[12];
  for(;;){
    bool ok = true;
    #pragma unroll
    for (int i=0;i<12;i++){
      x[i] = ldt_(base + 2*i);
      ok &= ((uint32_t)(x[i]>>32) == tag);
    }
    if (__all((int)ok)) break;
  }
  #pragma unroll
  for (int i=0;i<12;i++) out[i] = __uint_as_float((uint32_t)x[i]);
}

// ---------- prologue A ----------
__global__ void k_p0a(const float* __restrict__ z, const float* __restrict__ Winit,
    const float* __restrict__ binit, const float* __restrict__ W1, const float* __restrict__ b1,
    float* ws, float* out)
{
  int b = blockIdx.x; int tid = threadIdx.x;
  __shared__ float zs[H_];
  zs[tid] = z[b*H_ + tid];
  __syncthreads();
  float a0=0.f, a1=0.f;
  for (int k=0;k<H_;k++){
    float zv = zs[k];
    a0 += zv * Winit[(size_t)k*H_ + tid];
    a1 += zv * W1[(size_t)(2*H_ + k)*H_ + tid];
  }
  ws[H0_OFF + b*H_ + tid] = tanh_(a0 + binit[tid]);
  ws[ZC_OFF + b*H_ + tid] = a1 + b1[tid];
  if (b==0 && tid==0) out[LL_OUT] = 0.0f;
}

// ---------- prologue B: parent lists, tgt bitmasks, deg ----------
__global__ void k_p0b(const float* __restrict__ tgt, float* ws)
{
  int t = blockIdx.x, b = blockIdx.y, lane = threadIdx.x;
  uint32_t* wsu = (uint32_t*)ws;
  unsigned long long* ws64 = (unsigned long long*)ws;
  const float* row = tgt + ((size_t)(b*N_) + t)*N_;
  uint8_t* pl = ((uint8_t*)&wsu[PL_OFF]) + (size_t)(b*N_ + t)*N_;
  int cnt = 0;
  #pragma unroll
  for (int m=0;m<4;m++){
    float v = row[m*64 + lane];
    bool p = (v != 0.0f);
    unsigned long long bw = __ballot(p);
    if (lane == 0) ws64[TG64 + (size_t)(b*N_+t)*4 + m] = bw;
    if (p){
      int pos = cnt + (int)__popcll(bw & ((1ULL<<lane)-1ULL));
      pl[pos] = (uint8_t)(m*64 + lane);
    }
    cnt += (int)__popcll(bw);
  }
  if (lane == 0){
    wsu[PC_OFF + b*N_ + t] = (uint32_t)cnt;
    ws[DG_OFF + b*N_ + t] = 1.0f / fmaxf((float)cnt, 1.0f);
  }
}

// ---------- prologue C: children lists ----------
__global__ void k_p0c(float* ws)
{
  int j = blockIdx.x, b = blockIdx.y, lane = threadIdx.x;
  uint32_t* wsu = (uint32_t*)ws;
  unsigned long long* ws64 = (unsigned long long*)ws;
  uint8_t* cl = ((uint8_t*)&wsu[CL_OFF]) + (size_t)(b*N_ + j)*N_;
  int w = j >> 6; int sb = j & 63;
  int cnt = 0;
  #pragma unroll
  for (int m=0;m<4;m++){
    int t = m*64 + lane;
    unsigned long long rowm = ws64[TG64 + (size_t)(b*N_+t)*4 + w];
    bool p = ((rowm >> sb) & 1ULL) != 0ULL;
    unsigned long long bw = __ballot(p);
    if (p){
      int pos = cnt + (int)__popcll(bw & ((1ULL<<lane)-1ULL));
      cl[pos] = (uint8_t)t;
    }
    cnt += (int)__popcll(bw);
  }
  if (lane == 0) wsu[CC_OFF + b*N_ + j] = (uint32_t)cnt;
}

// ---------- ancestor chain (decoupled from pass1) ----------
__global__ void k_anc(float* ws)
{
  int b = blockIdx.x; int lane = threadIdx.x;
  unsigned long long* ws64 = (unsigned long long*)ws;
  uint32_t* wsu = (uint32_t*)ws;
  __shared__ unsigned long long AB[N_][4];
  if (lane < 4) AB[0][lane] = 0ULL;
  __syncthreads();
  int wq = lane & 3, pg = lane >> 2;
  for (int t=1; t<N_; t++){
    int npt = (int)wsu[PC_OFF + b*N_ + t];
    const uint8_t* pb = ((const uint8_t*)&wsu[PL_OFF]) + (size_t)(b*N_+t)*N_;
    unsigned long long acc = 0ULL;
    for (int i=pg; i<npt; i+=16) acc |= AB[pb[i]][wq];
    #pragma unroll
    for (int m=4; m<64; m<<=1) acc |= __shfl_xor(acc, m);
    if (lane < 4){
      ws64[AN64 + (size_t)(b*N_+t)*4 + lane] = acc;
      AB[t][lane] = acc | ws64[TG64 + (size_t)(b*N_+t)*4 + lane];
    }
    __syncthreads();
  }
}

// ---------- pass 1: sequential recurrence ----------
// 256 threads: tid<144 = matvec threads (g=tid>>4 col-group, kc=tid&15 k-chunk),
// wave3 = PS scatter. Per-thread register running-sum; all cross-block words are
// tagged u64 relaxed agent atomics (1-RT publish->consume, no fences, no waitcnt).
__global__ void __launch_bounds__(256) k_pass1(const float* __restrict__ z,
    const float* __restrict__ Wih, const float* __restrict__ Whh,
    const float* __restrict__ bih_g, const float* __restrict__ bhh_g,
    float* ws)
{
  int bx = blockIdx.x;
  int b = bx & 7;
  if (b >= B_) return;
  int slice = bx >> 3;
  int tid = threadIdx.x;
  float* wsf = ws;
  uint32_t* wsu = (uint32_t*)ws;
  unsigned long long* ws64 = (unsigned long long*)ws;

  __shared__ __align__(16) float sPS[N_*SC_];
  __shared__ __align__(16) float sa1[SC_];
  __shared__ __align__(16) float sa2[SC_];
  __shared__ __align__(16) float syy[SC_];
  __shared__ __align__(16) float sghz[SC_];
  __shared__ __align__(16) float sbih[SC_];
  __shared__ __align__(16) float sbhh[SC_];
  __shared__ __align__(16) float sdelta[SC_];

  const int g = tid >> 4;
  const int kc = tid & 15;
  const bool is_mv = (tid < MVT_);

  float rwih[12][4], rwhh[12][4];
  if (is_mv){
    int gate = (4*g)/12, cc = (4*g)%12;
    int gcol = gate*H_ + slice*SH_ + cc;
    #pragma unroll
    for (int i=0;i<12;i++){
      int k = kc*12 + i;
      float4 a = *(const float4*)(Wih + (size_t)k*H3_ + gcol);
      rwih[i][0]=a.x; rwih[i][1]=a.y; rwih[i][2]=a.z; rwih[i][3]=a.w;
      float4 c = *(const float4*)(Whh + (size_t)k*H3_ + gcol);
      rwhh[i][0]=c.x; rwhh[i][1]=c.y; rwhh[i][2]=c.z; rwhh[i][3]=c.w;
    }
  }
  if (tid < SC_){
    int gate = tid/12, cc = tid%12;
    sbih[tid] = bih_g[gate*H_ + slice*SH_ + cc];
    sbhh[tid] = bhh_g[gate*H_ + slice*SH_ + cc];
  }
  for (int i = tid; i < N_*SC_; i += 256) sPS[i] = 0.0f;
  float zreg = (tid < SH_) ? z[b*H_ + slice*SH_ + tid] : 0.0f;
  __syncthreads();

  // ghz = z@W_hh + b_hh (slice cols), constant over steps
  if (is_mv){
    float zv[12];
    #pragma unroll
    for (int i=0;i<12;i++) zv[i] = z[b*H_ + kc*12 + i];
    float a0=0,a1=0,a2=0,a3=0;
    #pragma unroll
    for (int i=0;i<12;i++){
      a0+=zv[i]*rwhh[i][0]; a1+=zv[i]*rwhh[i][1]; a2+=zv[i]*rwhh[i][2]; a3+=zv[i]*rwhh[i][3];
    }
    #pragma unroll
    for (int m=1;m<16;m<<=1){
      a0+=__shfl_xor(a0,m); a1+=__shfl_xor(a1,m); a2+=__shfl_xor(a2,m); a3+=__shfl_xor(a3,m);
    }
    if (kc==0){
      int c4=4*g;
      sghz[c4+0]=a0+sbhh[c4+0]; sghz[c4+1]=a1+sbhh[c4+1];
      sghz[c4+2]=a2+sbhh[c4+2]; sghz[c4+3]=a3+sbhh[c4+3];
    }
  }
  // publish S(0) = h0 slice (tag = 1), fire-and-forget
  if (tid < SH_){
    float v = wsf[H0_OFF + b*H_ + slice*SH_ + tid];
    stt_(&wsu[SL_OFF + (unsigned)(b*N_)*384u + (unsigned)(slice*SH_+tid)*2u], v, 1u);
  }
  __syncthreads();

  float qp0=0.f,qp1=0.f,qp2=0.f,qp3=0.f;
  float rsum[12];
  #pragma unroll
  for (int i=0;i<12;i++) rsum[i]=0.f;

  float dginv_cur = wsf[DG_OFF + b*N_ + 1];
  unsigned long long tw0 = ws64[TG64 + (size_t)(b*N_+1)*4];
  float tflag_cur = (float)(tw0 & 1ULL);

  float hp = 0.f, a2r=0.f, a2u=0.f, a2n=0.f;

  for (int t=1; t<N_; t++){
    const uint32_t tagS = (uint32_t)t;       // S(t-1) tag
    const uint32_t tagH = (uint32_t)(t+1);   // H(t)/S(t) tag
    // phase 1+2: poll S(t-1) chunk kc, fold into rsum, matvec1 + reduce
    if (is_mv){
      float v[12];
      poll12_(&wsu[SL_OFF + (unsigned)(b*N_+(t-1))*384u + (unsigned)kc*24u], tagS, v);
      #pragma unroll
      for (int i=0;i<12;i++) rsum[i] += v[i];
      float n0=0,n1=0,n2=0,n3=0;
      #pragma unroll
      for (int i=0;i<12;i++){
        n0+=rsum[i]*rwih[i][0]; n1+=rsum[i]*rwih[i][1];
        n2+=rsum[i]*rwih[i][2]; n3+=rsum[i]*rwih[i][3];
      }
      #pragma unroll
      for (int m=1;m<16;m<<=1){
        n0+=__shfl_xor(n0,m); n1+=__shfl_xor(n1,m);
        n2+=__shfl_xor(n2,m); n3+=__shfl_xor(n3,m);
      }
      if (kc == 0){
        int c4 = 4*g;
        float4 bb = *(float4*)&sbih[c4];
        float4 pv = *(float4*)&sPS[t*SC_ + c4];
        float invt = 1.0f/(float)t;
        float d0=n0-qp0, d1=n1-qp1, d2=n2-qp2, d3=n3-qp3;
        sa1[c4+0]=n0*invt+bb.x; sa1[c4+1]=n1*invt+bb.y;
        sa1[c4+2]=n2*invt+bb.z; sa1[c4+3]=n3*invt+bb.w;
        sa2[c4+0]=(pv.x+tflag_cur*d0)*dginv_cur+bb.x;
        sa2[c4+1]=(pv.y+tflag_cur*d1)*dginv_cur+bb.y;
        sa2[c4+2]=(pv.z+tflag_cur*d2)*dginv_cur+bb.z;
        sa2[c4+3]=(pv.w+tflag_cur*d3)*dginv_cur+bb.w;
        sdelta[c4+0]=d0; sdelta[c4+1]=d1; sdelta[c4+2]=d2; sdelta[c4+3]=d3;
      }
      qp0=n0; qp1=n1; qp2=n2; qp3=n3;
    }
    __syncthreads();   // B1: sa1/sa2/sdelta ready
    // phase 4: gates (wave0 lanes<12) publish H(t) | wave3: PS scatter of delta(t-1)
    if (tid < SH_){
      float r = sigm_(sa1[tid] + sghz[tid]);
      float u = sigm_(sa1[SH_+tid] + sghz[SH_+tid]);
      float n = tanh_(sa1[2*SH_+tid] + r*sghz[2*SH_+tid]);
      hp = (1.0f-u)*n + u*zreg;
      a2r = sa2[tid]; a2u = sa2[SH_+tid]; a2n = sa2[2*SH_+tid];
      stt_(&wsu[HL_OFF + (unsigned)(b*N_+t)*384u + (unsigned)(slice*SH_+tid)*2u], hp, tagH);
    } else if (tid >= 192 && tid < 192+SC_){
      int c = tid - 192;
      int ccn = (int)wsu[CC_OFF + b*N_ + (t-1)];
      const uint8_t* cl = ((const uint8_t*)&wsu[CL_OFF]) + (size_t)(b*N_ + (t-1))*N_;
      float d = sdelta[c];
      for (int i=0;i<ccn;i++){
        int tc = cl[i];
        if (tc != t) sPS[tc*SC_ + c] += d;
      }
    }
    // phase 5: poll H(t) chunk kc, matvec2 + reduce
    if (is_mv){
      float hv[12];
      poll12_(&wsu[HL_OFF + (unsigned)(b*N_+t)*384u + (unsigned)kc*24u], tagH, hv);
      float y0=0,y1=0,y2=0,y3=0;
      #pragma unroll
      for (int i=0;i<12;i++){
        y0+=hv[i]*rwhh[i][0]; y1+=hv[i]*rwhh[i][1];
        y2+=hv[i]*rwhh[i][2]; y3+=hv[i]*rwhh[i][3];
      }
      #pragma unroll
      for (int m=1;m<16;m<<=1){
        y0+=__shfl_xor(y0,m); y1+=__shfl_xor(y1,m);
        y2+=__shfl_xor(y2,m); y3+=__shfl_xor(y3,m);
      }
      if (kc == 0){
        int c4=4*g;
        syy[c4+0]=y0; syy[c4+1]=y1; syy[c4+2]=y2; syy[c4+3]=y3;
      }
    }
    __syncthreads();   // B2: syy ready; wave3 scatter done before next PS read
    // phase 7: h_new (lanes<12), publish S(t)
    if (tid < SH_){
      float gr = syy[tid] + sbhh[tid];
      float gu = syy[SH_+tid] + sbhh[SH_+tid];
      float gn = syy[2*SH_+tid] + sbhh[2*SH_+tid];
      float r2 = sigm_(a2r + gr);
      float u2 = sigm_(a2u + gu);
      float n2 = tanh_(a2n + r2*gn);
      float hn = (1.0f-u2)*n2 + u2*hp;
      stt_(&wsu[SL_OFF + (unsigned)(b*N_+t)*384u + (unsigned)(slice*SH_+tid)*2u], hn, tagH);
    }
    if (is_mv && t < N_-1){
      dginv_cur = wsf[DG_OFF + b*N_ + t + 1];
      unsigned long long tw = ws64[TG64 + (size_t)(b*N_ + t + 1)*4 + (t>>6)];
      tflag_cur = (float)((tw >> (t & 63)) & 1ULL);
    }
  }
}

// ---------- pass 2a: G = S@W1b, C = Hprov@W1a + zc, NF = S@Wf + bf ----------
__global__ void k_p2a(const float* __restrict__ W1, const float* __restrict__ Wf,
    const float* __restrict__ bf, float* ws, float* out)
{
  int j = blockIdx.x, b = blockIdx.y, tid = threadIdx.x;
  __shared__ float srow[H_], hrow[H_];
  __shared__ float nfp[3][F_];
  srow[tid] = ws[SL_OFF + (unsigned)(b*N_+j)*384u + 2u*tid];
  hrow[tid] = ws[HL_OFF + (unsigned)(b*N_+j)*384u + 2u*tid];   // garbage for j=0, C[0] unused
  __syncthreads();
  float accG = 0.f, accC = 0.f;
  for (int k=0;k<H_;k++){
    float sv = srow[k], hv = hrow[k];
    accG += sv * W1[(size_t)(H_+k)*H_ + tid];
    accC += hv * W1[(size_t)k*H_ + tid];
  }
  ws[G_OFF + (size_t)(b*N_+j)*H_ + tid] = accG;
  ws[C_OFF + (size_t)(b*N_+j)*H_ + tid] = accC + ws[ZC_OFF + b*H_ + tid];
  int f = tid & 63, kp = tid >> 6;
  float a = 0.f;
  for (int i=0;i<64;i++){ int k = kp*64 + i; a += srow[k]*Wf[(size_t)k*F_ + f]; }
  nfp[kp][f] = a;
  __syncthreads();
  if (tid < F_) out[NF_OUT + (size_t)(b*N_+j)*F_ + tid] = nfp[0][tid]+nfp[1][tid]+nfp[2][tid] + bf[tid];
}

// ---------- pass 2b: log-likelihood ----------
__global__ void __launch_bounds__(256) k_p2b(const float* __restrict__ W2,
    const float* __restrict__ b2p, float* ws, float* out)
{
  int t = blockIdx.x + 1, b = blockIdx.y;
  int tid = threadIdx.x; int lane = tid & 63; int wv = tid >> 6;
  __shared__ float cvec[H_], sw2[H_];
  __shared__ float wsum[4];
  __shared__ unsigned long long sanc[4], stgt[4];
  unsigned long long* ws64 = (unsigned long long*)ws;
  if (tid < H_){
    cvec[tid] = ws[C_OFF + (size_t)(b*N_+t)*H_ + tid];
    sw2[tid] = W2[tid];
  }
  if (tid < 4){
    sanc[tid] = ws64[AN64 + (size_t)(b*N_+t)*4 + tid];
    stgt[tid] = ws64[TG64 + (size_t)(b*N_+t)*4 + tid];
  }
  __syncthreads();
  float b2s = b2p[0];
  float c0 = cvec[lane], c1 = cvec[64+lane], c2 = cvec[128+lane];
  float w20 = sw2[lane], w21 = sw2[64+lane], w22 = sw2[128+lane];
  const float* Gb = ws + G_OFF + (size_t)(b*N_)*H_;
  float acc = 0.f;
  for (int j = wv; j < t; j += 4){
    const float* gr = Gb + (size_t)j*H_;
    float p0 = fmaxf(c0 + gr[lane], 0.f)*w20
             + fmaxf(c1 + gr[64+lane], 0.f)*w21
             + fmaxf(c2 + gr[128+lane], 0.f)*w22;
    #pragma unroll
    for (int m=32;m>=1;m>>=1) p0 += __shfl_xor(p0, m);
    if (lane == 0){
      float logit = p0 + b2s;
      float pp = 1.0f/(1.0f+__expf(-logit));
      float anc = (float)((sanc[j>>6] >> (j&63)) & 1ULL);
      pp = pp * (1.0f - anc);
      pp = fminf(fmaxf(pp, 1e-6f), 1.0f - 1e-6f);
      int tg = (int)((stgt[j>>6] >> (j&63)) & 1ULL);
      acc += tg ? logf(pp) : log1pf(-pp);
    }
  }
  if (lane == 0) wsum[wv] = acc;
  __syncthreads();
  if (tid == 0) atomicAdd(out + LL_OUT, wsum[0]+wsum[1]+wsum[2]+wsum[3]);
}

extern "C" void kernel_launch(void* const* d_in, const int* in_sizes, int n_in,
                              void* d_out, int out_size, void* d_ws, size_t ws_size,
                              hipStream_t stream) {
  (void)in_sizes; (void)n_in; (void)out_size; (void)ws_size;
  const float* z     = (const float*)d_in[0];
  const float* tgt   = (const float*)d_in[1];
  const float* Winit = (const float*)d_in[2];
  const float* binit = (const float*)d_in[3];
  const float* Wih   = (const float*)d_in[4];
  const float* Whh   = (const float*)d_in[5];
  const float* bih   = (const float*)d_in[6];
  const float* bhh   = (const float*)d_in[7];
  const float* W1    = (const float*)d_in[8];
  const float* b1    = (const float*)d_in[9];
  const float* W2    = (const float*)d_in[10];
  const float* b2    = (const float*)d_in[11];
  const float* Wf    = (const float*)d_in[12];
  const float* bf    = (const float*)d_in[13];
  float* out = (float*)d_out;
  float* ws  = (float*)d_ws;

  hipMemcpyAsync(d_out, d_in[1], (size_t)B_*N_*N_*sizeof(float), hipMemcpyDeviceToDevice, stream);

  k_p0a<<<dim3(B_), dim3(H_), 0, stream>>>(z, Winit, binit, W1, b1, ws, out);
  k_p0b<<<dim3(N_, B_), dim3(64), 0, stream>>>(tgt, ws);
  k_p0c<<<dim3(N_, B_), dim3(64), 0, stream>>>(ws);
  k_anc<<<dim3(B_), dim3(64), 0, stream>>>(ws);
  k_pass1<<<dim3(128), dim3(256), 0, stream>>>(z, Wih, Whh, bih, bhh, ws);
  k_p2a<<<dim3(N_, B_), dim3(H_), 0, stream>>>(W1, Wf, bf, ws, out);
  k_p2b<<<dim3(N_-1, B_), dim3(256), 0, stream>>>(W2, b2, ws, out);
}

// Round 4
// 1155.940 us; speedup vs baseline: 1.2725x; 1.2725x over previous
//
#include <hip/hip_runtime.h>
#include <stdint.h>

#define B_ 4
#define N_ 256
#define H_ 192
#define H3_ 576
#define F_ 64
#define SH_ 12      // hidden per slice (16 slices)
#define SC_ 36      // 3 gates * SH_
#define MVT_ 144    // 9 col-groups * 16 k-chunks

// ---- workspace layout (32-bit words) ----
// HL/SL rows are 192 tagged u64 elements: (low32 = fp32 bits, high32 = tag = t+1).
#define H0_OFF   0u
#define ZC_OFF   1024u
#define HL_OFF   2048u        // [b][t][192] tagged h_prov, 384 words/row
#define SL_OFF   395264u      // [b][t][192] tagged S rows
#define AN_OFF   788480u      // [b][t][4] u64 ancestor masks
#define TG_OFF   796672u      // [b][t][4] u64 target masks
#define PL_OFF   804864u      // parent lists (u8)
#define PC_OFF   870400u      // parent counts
#define DG_OFF   871424u      // 1/deg
#define G_OFF    872448u      // G^T: [b][k][N] (S@W1b transposed)
#define C_OFF    1069056u     // Hprov@W1a + zc
#define CL_OFF   1265664u     // children lists (u8)
#define CC_OFF   1331200u     // children counts

#define AN64 (AN_OFF/2)
#define TG64 (TG_OFF/2)

#define NF_OUT 262144u
#define LL_OUT 327680u

__device__ __forceinline__ float sigm_(float x){ return 1.0f/(1.0f + __expf(-x)); }
__device__ __forceinline__ float tanh_(float x){
  float ax = fabsf(x);
  float e = __expf(-2.0f*ax);
  float t = (1.0f - e)/(1.0f + e);
  return x < 0.0f ? -t : t;
}

// tagged 64-bit publish/poll: single-copy-atomic u64 = (tag<<32)|fp32bits, agent scope (sc1).
__device__ __forceinline__ void stt_(uint32_t* p, float v, uint32_t tag){
  unsigned long long u = ((unsigned long long)tag<<32) | (unsigned long long)__float_as_uint(v);
  __hip_atomic_store((unsigned long long*)p, u, __ATOMIC_RELAXED, __HIP_MEMORY_SCOPE_AGENT);
}
__device__ __forceinline__ unsigned long long ldt_(const uint32_t* p){
  return __hip_atomic_load((const unsigned long long*)p, __ATOMIC_RELAXED, __HIP_MEMORY_SCOPE_AGENT);
}
// wave-parallel poll: ONE tagged u64 per lane per iteration (1 RT / iter).
__device__ __forceinline__ float poll1_(const uint32_t* p, uint32_t tag){
  unsigned long long x;
  do { x = ldt_(p); } while (__all((int)((uint32_t)(x>>32) == tag)) == 0);
  return __uint_as_float((uint32_t)x);
}

// ---------- pre1: (bx<N_): parent lists/bitmasks/deg | (bx==N_): h0, zc, ll=0 ----------
__global__ void __launch_bounds__(192) k_pre1(const float* __restrict__ z,
    const float* __restrict__ Winit, const float* __restrict__ binit,
    const float* __restrict__ W1, const float* __restrict__ b1,
    const float* __restrict__ tgt, float* ws, float* out)
{
  int bx = blockIdx.x, b = blockIdx.y, tid = threadIdx.x;
  if (bx == N_){
    __shared__ float zs[H_];
    zs[tid] = z[b*H_ + tid];
    __syncthreads();
    float a0=0.f, a1=0.f;
    for (int k=0;k<H_;k++){
      float zv = zs[k];
      a0 += zv * Winit[(size_t)k*H_ + tid];
      a1 += zv * W1[(size_t)(2*H_ + k)*H_ + tid];
    }
    ws[H0_OFF + b*H_ + tid] = tanh_(a0 + binit[tid]);
    ws[ZC_OFF + b*H_ + tid] = a1 + b1[tid];
    if (b==0 && tid==0) out[LL_OUT] = 0.0f;
    return;
  }
  if (tid >= 64) return;
  int t = bx, lane = tid;
  uint32_t* wsu = (uint32_t*)ws;
  unsigned long long* ws64 = (unsigned long long*)ws;
  const float* row = tgt + ((size_t)(b*N_) + t)*N_;
  uint8_t* pl = ((uint8_t*)&wsu[PL_OFF]) + (size_t)(b*N_ + t)*N_;
  int cnt = 0;
  #pragma unroll
  for (int m=0;m<4;m++){
    float v = row[m*64 + lane];
    bool p = (v != 0.0f);
    unsigned long long bw = __ballot(p);
    if (lane == 0) ws64[TG64 + (size_t)(b*N_+t)*4 + m] = bw;
    if (p){
      int pos = cnt + (int)__popcll(bw & ((1ULL<<lane)-1ULL));
      pl[pos] = (uint8_t)(m*64 + lane);
    }
    cnt += (int)__popcll(bw);
  }
  if (lane == 0){
    wsu[PC_OFF + b*N_ + t] = (uint32_t)cnt;
    ws[DG_OFF + b*N_ + t] = 1.0f / fmaxf((float)cnt, 1.0f);
  }
}

// ---------- pre2: (bx<N_): children lists | (bx==N_): ancestor chain ----------
__global__ void __launch_bounds__(64) k_pre2(float* ws)
{
  int bx = blockIdx.x, b = blockIdx.y, lane = threadIdx.x;
  uint32_t* wsu = (uint32_t*)ws;
  unsigned long long* ws64 = (unsigned long long*)ws;
  if (bx < N_){
    int j = bx;
    uint8_t* cl = ((uint8_t*)&wsu[CL_OFF]) + (size_t)(b*N_ + j)*N_;
    int w = j >> 6; int sb = j & 63;
    int cnt = 0;
    #pragma unroll
    for (int m=0;m<4;m++){
      int t = m*64 + lane;
      unsigned long long rowm = ws64[TG64 + (size_t)(b*N_+t)*4 + w];
      bool p = ((rowm >> sb) & 1ULL) != 0ULL;
      unsigned long long bw = __ballot(p);
      if (p){
        int pos = cnt + (int)__popcll(bw & ((1ULL<<lane)-1ULL));
        cl[pos] = (uint8_t)t;
      }
      cnt += (int)__popcll(bw);
    }
    if (lane == 0) wsu[CC_OFF + b*N_ + j] = (uint32_t)cnt;
    return;
  }
  // ancestor chain for batch b
  __shared__ unsigned long long AB[N_][4];
  if (lane < 4) AB[0][lane] = 0ULL;
  __syncthreads();
  int wq = lane & 3, pg = lane >> 2;
  for (int t=1; t<N_; t++){
    int npt = (int)wsu[PC_OFF + b*N_ + t];
    const uint8_t* pb = ((const uint8_t*)&wsu[PL_OFF]) + (size_t)(b*N_+t)*N_;
    unsigned long long acc = 0ULL;
    for (int i=pg; i<npt; i+=16) acc |= AB[pb[i]][wq];
    #pragma unroll
    for (int m=4; m<64; m<<=1) acc |= __shfl_xor(acc, m);
    if (lane < 4){
      ws64[AN64 + (size_t)(b*N_+t)*4 + lane] = acc;
      AB[t][lane] = acc | ws64[TG64 + (size_t)(b*N_+t)*4 + lane];
    }
    __syncthreads();
  }
}

// ---------- pass 1: sequential recurrence ----------
// 256 threads/block, 16 slice-blocks per batch (blockIdx%8 = batch for XCD locality).
// tid<192: wave-parallel pollers (lane e polls tagged element e, 1 load/iter) and
// tid<144 are matvec threads (g=tid>>4 col-group, kc=tid&15 k-chunk). Wave3: PS scatter.
__global__ void __launch_bounds__(256) k_pass1(const float* __restrict__ z,
    const float* __restrict__ Wih, const float* __restrict__ Whh,
    const float* __restrict__ bih_g, const float* __restrict__ bhh_g,
    float* ws)
{
  int bx = blockIdx.x;
  int b = bx & 7;
  if (b >= B_) return;
  int slice = bx >> 3;
  int tid = threadIdx.x;
  float* wsf = ws;
  uint32_t* wsu = (uint32_t*)ws;
  unsigned long long* ws64 = (unsigned long long*)ws;

  __shared__ __align__(16) float sruns[H_];   // running sum of S rows (LDS-resident)
  __shared__ __align__(16) float sh[H_];      // gathered h_prov
  __shared__ __align__(16) float sPS[N_*SC_];
  __shared__ __align__(16) float sa1[SC_];
  __shared__ __align__(16) float sa2[SC_];
  __shared__ __align__(16) float syy[SC_];
  __shared__ __align__(16) float sghz[SC_];
  __shared__ __align__(16) float sbih[SC_];
  __shared__ __align__(16) float sbhh[SC_];
  __shared__ __align__(16) float sdelta[SC_];

  const int g = tid >> 4;
  const int kc = tid & 15;
  const bool is_mv = (tid < MVT_);

  float rwih[12][4], rwhh[12][4];
  if (is_mv){
    int gate = (4*g)/12, cc = (4*g)%12;
    int gcol = gate*H_ + slice*SH_ + cc;
    #pragma unroll
    for (int i=0;i<12;i++){
      int k = kc*12 + i;
      float4 a = *(const float4*)(Wih + (size_t)k*H3_ + gcol);
      rwih[i][0]=a.x; rwih[i][1]=a.y; rwih[i][2]=a.z; rwih[i][3]=a.w;
      float4 c = *(const float4*)(Whh + (size_t)k*H3_ + gcol);
      rwhh[i][0]=c.x; rwhh[i][1]=c.y; rwhh[i][2]=c.z; rwhh[i][3]=c.w;
    }
  }
  if (tid < SC_){
    int gate = tid/12, cc = tid%12;
    sbih[tid] = bih_g[gate*H_ + slice*SH_ + cc];
    sbhh[tid] = bhh_g[gate*H_ + slice*SH_ + cc];
  }
  if (tid < H_) sruns[tid] = 0.0f;
  for (int i = tid; i < N_*SC_; i += 256) sPS[i] = 0.0f;
  float zreg = (tid < SH_) ? z[b*H_ + slice*SH_ + tid] : 0.0f;
  __syncthreads();

  // ghz = z@W_hh + b_hh (slice cols), constant over steps
  if (is_mv){
    float zv[12];
    #pragma unroll
    for (int i=0;i<12;i++) zv[i] = z[b*H_ + kc*12 + i];
    float a0=0,a1=0,a2=0,a3=0;
    #pragma unroll
    for (int i=0;i<12;i++){
      a0+=zv[i]*rwhh[i][0]; a1+=zv[i]*rwhh[i][1]; a2+=zv[i]*rwhh[i][2]; a3+=zv[i]*rwhh[i][3];
    }
    #pragma unroll
    for (int m=1;m<16;m<<=1){
      a0+=__shfl_xor(a0,m); a1+=__shfl_xor(a1,m); a2+=__shfl_xor(a2,m); a3+=__shfl_xor(a3,m);
    }
    if (kc==0){
      int c4=4*g;
      sghz[c4+0]=a0+sbhh[c4+0]; sghz[c4+1]=a1+sbhh[c4+1];
      sghz[c4+2]=a2+sbhh[c4+2]; sghz[c4+3]=a3+sbhh[c4+3];
    }
  }
  // publish S(0) = h0 slice (tag = 1)
  if (tid < SH_){
    float v = wsf[H0_OFF + b*H_ + slice*SH_ + tid];
    stt_(&wsu[SL_OFF + (unsigned)(b*N_)*384u + (unsigned)(slice*SH_+tid)*2u], v, 1u);
  }
  __syncthreads();

  float qp0=0.f,qp1=0.f,qp2=0.f,qp3=0.f;
  float dginv_cur = wsf[DG_OFF + b*N_ + 1];
  unsigned long long tw0 = ws64[TG64 + (size_t)(b*N_+1)*4];
  float tflag_cur = (float)(tw0 & 1ULL);
  float hp = 0.f, a2r=0.f, a2u=0.f, a2n=0.f;

  for (int t=1; t<N_; t++){
    const uint32_t tagS = (uint32_t)t;
    const uint32_t tagH = (uint32_t)(t+1);
    // phase A: poll S(t-1) element tid (1 load/lane/iter), fold into sruns
    if (tid < 192){
      float v = poll1_(&wsu[SL_OFF + (unsigned)(b*N_+(t-1))*384u + 2u*(unsigned)tid], tagS);
      sruns[tid] += v;
    }
    __syncthreads();   // B1
    // phase B: mv1 = sruns@Wih(slice cols) + per-col outputs
    if (is_mv){
      const float* rs = &sruns[kc*12];
      float n0=0,n1=0,n2=0,n3=0;
      #pragma unroll
      for (int i=0;i<12;i++){
        float xv = rs[i];
        n0+=xv*rwih[i][0]; n1+=xv*rwih[i][1]; n2+=xv*rwih[i][2]; n3+=xv*rwih[i][3];
      }
      #pragma unroll
      for (int m=1;m<16;m<<=1){
        n0+=__shfl_xor(n0,m); n1+=__shfl_xor(n1,m);
        n2+=__shfl_xor(n2,m); n3+=__shfl_xor(n3,m);
      }
      if (kc == 0){
        int c4 = 4*g;
        float4 bb = *(float4*)&sbih[c4];
        float4 pv = *(float4*)&sPS[t*SC_ + c4];
        float invt = 1.0f/(float)t;
        float d0=n0-qp0, d1=n1-qp1, d2=n2-qp2, d3=n3-qp3;
        sa1[c4+0]=n0*invt+bb.x; sa1[c4+1]=n1*invt+bb.y;
        sa1[c4+2]=n2*invt+bb.z; sa1[c4+3]=n3*invt+bb.w;
        sa2[c4+0]=(pv.x+tflag_cur*d0)*dginv_cur+bb.x;
        sa2[c4+1]=(pv.y+tflag_cur*d1)*dginv_cur+bb.y;
        sa2[c4+2]=(pv.z+tflag_cur*d2)*dginv_cur+bb.z;
        sa2[c4+3]=(pv.w+tflag_cur*d3)*dginv_cur+bb.w;
        sdelta[c4+0]=d0; sdelta[c4+1]=d1; sdelta[c4+2]=d2; sdelta[c4+3]=d3;
      }
      qp0=n0; qp1=n1; qp2=n2; qp3=n3;
    }
    __syncthreads();   // B2
    // phase C: gates1 (lanes<12) -> publish H(t); pollers gather H; wave3 scatters
    if (tid < SH_){
      float r = sigm_(sa1[tid] + sghz[tid]);
      float u = sigm_(sa1[SH_+tid] + sghz[SH_+tid]);
      float n = tanh_(sa1[2*SH_+tid] + r*sghz[2*SH_+tid]);
      hp = (1.0f-u)*n + u*zreg;
      a2r = sa2[tid]; a2u = sa2[SH_+tid]; a2n = sa2[2*SH_+tid];
      stt_(&wsu[HL_OFF + (unsigned)(b*N_+t)*384u + (unsigned)(slice*SH_+tid)*2u], hp, tagH);
    }
    if (tid < 192){
      float v = poll1_(&wsu[HL_OFF + (unsigned)(b*N_+t)*384u + 2u*(unsigned)tid], tagH);
      sh[tid] = v;
    } else if (tid < 192+SC_){
      int c = tid - 192;
      int ccn = (int)wsu[CC_OFF + b*N_ + (t-1)];
      const uint8_t* cl = ((const uint8_t*)&wsu[CL_OFF]) + (size_t)(b*N_ + (t-1))*N_;
      float d = sdelta[c];
      for (int i=0;i<ccn;i++){
        int tc = cl[i];
        if (tc != t) sPS[tc*SC_ + c] += d;
      }
    }
    __syncthreads();   // B3
    // phase D: mv2 = sh@Whh(slice cols)
    if (is_mv){
      const float* hs = &sh[kc*12];
      float y0=0,y1=0,y2=0,y3=0;
      #pragma unroll
      for (int i=0;i<12;i++){
        float hv = hs[i];
        y0+=hv*rwhh[i][0]; y1+=hv*rwhh[i][1]; y2+=hv*rwhh[i][2]; y3+=hv*rwhh[i][3];
      }
      #pragma unroll
      for (int m=1;m<16;m<<=1){
        y0+=__shfl_xor(y0,m); y1+=__shfl_xor(y1,m);
        y2+=__shfl_xor(y2,m); y3+=__shfl_xor(y3,m);
      }
      if (kc == 0){
        int c4=4*g;
        syy[c4+0]=y0; syy[c4+1]=y1; syy[c4+2]=y2; syy[c4+3]=y3;
      }
    }
    __syncthreads();   // B4
    // phase E: gates2 (lanes<12) -> publish S(t)
    if (tid < SH_){
      float gr = syy[tid] + sbhh[tid];
      float gu = syy[SH_+tid] + sbhh[SH_+tid];
      float gn = syy[2*SH_+tid] + sbhh[2*SH_+tid];
      float r2 = sigm_(a2r + gr);
      float u2 = sigm_(a2u + gu);
      float n2 = tanh_(a2n + r2*gn);
      float hn = (1.0f-u2)*n2 + u2*hp;
      stt_(&wsu[SL_OFF + (unsigned)(b*N_+t)*384u + (unsigned)(slice*SH_+tid)*2u], hn, tagH);
    }
    if (is_mv && kc==0 && t < N_-1){
      dginv_cur = wsf[DG_OFF + b*N_ + t + 1];
      unsigned long long tw = ws64[TG64 + (size_t)(b*N_ + t + 1)*4 + (t>>6)];
      tflag_cur = (float)((tw >> (t & 63)) & 1ULL);
    }
  }
}

// ---------- pass 2a: G^T = (S@W1b)^T, C = Hprov@W1a + zc, NF = S@Wf + bf ----------
__global__ void k_p2a(const float* __restrict__ W1, const float* __restrict__ Wf,
    const float* __restrict__ bf, float* ws, float* out)
{
  int j = blockIdx.x, b = blockIdx.y, tid = threadIdx.x;
  __shared__ float srow[H_], hrow[H_];
  __shared__ float nfp[3][F_];
  srow[tid] = ws[SL_OFF + (unsigned)(b*N_+j)*384u + 2u*tid];
  hrow[tid] = ws[HL_OFF + (unsigned)(b*N_+j)*384u + 2u*tid];   // garbage for j=0, C[0] unused
  __syncthreads();
  float accG = 0.f, accC = 0.f;
  for (int k=0;k<H_;k++){
    float sv = srow[k], hv = hrow[k];
    accG += sv * W1[(size_t)(H_+k)*H_ + tid];
    accC += hv * W1[(size_t)k*H_ + tid];
  }
  ws[G_OFF + ((size_t)b*H_ + tid)*N_ + j] = accG;    // transposed store
  ws[C_OFF + (size_t)(b*N_+j)*H_ + tid] = accC + ws[ZC_OFF + b*H_ + tid];
  int f = tid & 63, kp = tid >> 6;
  float a = 0.f;
  for (int i=0;i<64;i++){ int k = kp*64 + i; a += srow[k]*Wf[(size_t)k*F_ + f]; }
  nfp[kp][f] = a;
  __syncthreads();
  if (tid < F_) out[NF_OUT + (size_t)(b*N_+j)*F_ + tid] = nfp[0][tid]+nfp[1][tid]+nfp[2][tid] + bf[tid];
}

// ---------- pass 2b: log-likelihood, lane-per-candidate-parent ----------
__global__ void __launch_bounds__(256) k_p2b(const float* __restrict__ W2,
    const float* __restrict__ b2p, float* ws, float* out)
{
  int t = blockIdx.x + 1, b = blockIdx.y;
  int tid = threadIdx.x; int lane = tid & 63; int wv = tid >> 6;
  __shared__ float cv[H_], w2s[H_];
  __shared__ float wsum[4];
  unsigned long long* ws64 = (unsigned long long*)ws;
  if (tid < H_){
    cv[tid] = ws[C_OFF + (size_t)(b*N_+t)*H_ + tid];
    w2s[tid] = W2[tid];
  }
  __syncthreads();
  float acc = 0.f;
  if (tid < t){
    const float* GT = ws + G_OFF + (size_t)b*H_*N_;
    float a = 0.f;
    for (int k=0;k<H_;k++) a += fmaxf(cv[k] + GT[(size_t)k*N_ + tid], 0.f) * w2s[k];
    float logit = a + b2p[0];
    float pp = 1.0f/(1.0f+__expf(-logit));
    unsigned long long an = ws64[AN64 + (size_t)(b*N_+t)*4 + (tid>>6)];
    unsigned long long tg = ws64[TG64 + (size_t)(b*N_+t)*4 + (tid>>6)];
    float anc = (float)((an >> (tid&63)) & 1ULL);
    pp = pp * (1.0f - anc);
    pp = fminf(fmaxf(pp, 1e-6f), 1.0f - 1e-6f);
    int tgb = (int)((tg >> (tid&63)) & 1ULL);
    acc = tgb ? logf(pp) : log1pf(-pp);
  }
  #pragma unroll
  for (int m=32;m>=1;m>>=1) acc += __shfl_xor(acc, m);
  if (lane == 0) wsum[wv] = acc;
  __syncthreads();
  if (tid == 0) atomicAdd(out + LL_OUT, wsum[0]+wsum[1]+wsum[2]+wsum[3]);
}

extern "C" void kernel_launch(void* const* d_in, const int* in_sizes, int n_in,
                              void* d_out, int out_size, void* d_ws, size_t ws_size,
                              hipStream_t stream) {
  (void)in_sizes; (void)n_in; (void)out_size; (void)ws_size;
  const float* z     = (const float*)d_in[0];
  const float* tgt   = (const float*)d_in[1];
  const float* Winit = (const float*)d_in[2];
  const float* binit = (const float*)d_in[3];
  const float* Wih   = (const float*)d_in[4];
  const float* Whh   = (const float*)d_in[5];
  const float* bih   = (const float*)d_in[6];
  const float* bhh   = (const float*)d_in[7];
  const float* W1    = (const float*)d_in[8];
  const float* b1    = (const float*)d_in[9];
  const float* W2    = (const float*)d_in[10];
  const float* b2    = (const float*)d_in[11];
  const float* Wf    = (const float*)d_in[12];
  const float* bf    = (const float*)d_in[13];
  float* out = (float*)d_out;
  float* ws  = (float*)d_ws;

  hipMemcpyAsync(d_out, d_in[1], (size_t)B_*N_*N_*sizeof(float), hipMemcpyDeviceToDevice, stream);

  k_pre1<<<dim3(N_+1, B_), dim3(192), 0, stream>>>(z, Winit, binit, W1, b1, tgt, ws, out);
  k_pre2<<<dim3(N_+1, B_), dim3(64), 0, stream>>>(ws);
  k_pass1<<<dim3(128), dim3(256), 0, stream>>>(z, Wih, Whh, bih, bhh, ws);
  k_p2a<<<dim3(N_, B_), dim3(H_), 0, stream>>>(W1, Wf, bf, ws, out);
  k_p2b<<<dim3(N_-1, B_), dim3(256), 0, stream>>>(W2, b2, ws, out);
}

// Round 6
// 932.670 us; speedup vs baseline: 1.5771x; 1.2394x over previous
//
#include <hip/hip_runtime.h>
#include <stdint.h>

#define B_ 4
#define N_ 256
#define H_ 192
#define H3_ 576
#define F_ 64
#define SH_ 12      // hidden per slice (16 slices)
#define SC_ 36      // 3 gates * SH_

// ---- workspace layout (32-bit words) ----
// HL/SL (MALL) and FHL/FSL (fast, XCD-L2) rows are 192 tagged u64:
// high32 = tag (t+1), low32 = fp32 bits. Tags 1..256; 0xAAAAAAAA poison never matches.
#define H0_OFF   0u
#define ZC_OFF   1024u
#define HL_OFF   2048u        // MALL h_prov rows [b][t][192] u64
#define SL_OFF   395264u      // MALL S rows
#define AN_OFF   788480u      // [b][t][4] u64 ancestor masks
#define TG_OFF   796672u      // [b][t][4] u64 target masks
#define PL_OFF   804864u      // parent lists (u8)
#define PC_OFF   870400u      // parent counts
#define DG_OFF   871424u      // 1/deg
#define G_OFF    872448u      // G^T: [b][k][N]
#define C_OFF    1069056u     // Hprov@W1a + zc
#define CL_OFF   1265664u     // children lists (u8)
#define CC_OFF   1331200u     // children counts
#define XC_OFF   1332224u     // [b][16] xcd-id exchange words
#define FHL_OFF  1332288u     // fast (XCD-L2) h_prov rows
#define FSL_OFF  1725504u     // fast (XCD-L2) S rows

#define AN64 (AN_OFF/2)
#define TG64 (TG_OFF/2)

#define NF_OUT 262144u
#define LL_OUT 327680u

__device__ __forceinline__ float sigm_(float x){ return 1.0f/(1.0f + __expf(-x)); }
__device__ __forceinline__ float tanh_(float x){
  float ax = fabsf(x);
  float e = __expf(-2.0f*ax);
  float t = (1.0f - e)/(1.0f + e);
  return x < 0.0f ? -t : t;
}

// MALL (agent/sc1) tagged ops — proven in r3/r4.
__device__ __forceinline__ void st_mall_(uint32_t* p, unsigned long long u){
  __hip_atomic_store((unsigned long long*)p, u, __ATOMIC_RELAXED, __HIP_MEMORY_SCOPE_AGENT);
}
__device__ __forceinline__ unsigned long long ld_mall_(const uint32_t* p){
  return __hip_atomic_load((const unsigned long long*)p, __ATOMIC_RELAXED, __HIP_MEMORY_SCOPE_AGENT);
}
// fast-path load: invalidate L1 (sc0 level only), then plain load -> hits shared XCD L2.
__device__ __forceinline__ unsigned long long ld_l2_(const uint32_t* p){
  unsigned long long v;
  asm volatile("buffer_inv sc0\n\t"
               "s_waitcnt vmcnt(0)\n\t"
               "global_load_dwordx2 %0, %1, off\n\t"
               "s_waitcnt vmcnt(0)"
               : "=v"(v) : "v"(p) : "memory");
  return v;
}
// dual publish: plain write-through store (own XCD L2) + sc1 store (MALL).
__device__ __forceinline__ void pub_(uint32_t* fp, uint32_t* mp, float v, uint32_t tag){
  unsigned long long u = ((unsigned long long)tag<<32) | (unsigned long long)__float_as_uint(v);
  __hip_atomic_store((unsigned long long*)fp, u, __ATOMIC_RELAXED, __HIP_MEMORY_SCOPE_WORKGROUP);
  st_mall_(mp, u);
}
// hang-proof hybrid poll: fast lanes spin on L2 copy, every 4th iter also accept the
// MALL copy; non-fast lanes spin on MALL only (r4-proven). One u64 per lane per iter.
__device__ __forceinline__ float pollH_(const uint32_t* fp, const uint32_t* mp, int fast, uint32_t tag){
  unsigned long long x = 0; int it = 0;
  for(;;){
    if (fast){
      x = ld_l2_(fp);
      if ((uint32_t)(x>>32) != tag && (((++it) & 3) == 3)){
        unsigned long long m = ld_mall_(mp);
        if ((uint32_t)(m>>32) == tag) x = m;
      }
    } else {
      x = ld_mall_(mp);
    }
    if (__all((int)((uint32_t)(x>>32) == tag))) break;
  }
  return __uint_as_float((uint32_t)x);
}

// ---------- pre1: (bx<N_): parent lists/bitmasks/deg | (bx==N_): h0, zc, ll=0 ----------
__global__ void __launch_bounds__(192) k_pre1(const float* __restrict__ z,
    const float* __restrict__ Winit, const float* __restrict__ binit,
    const float* __restrict__ W1, const float* __restrict__ b1,
    const float* __restrict__ tgt, float* ws, float* out)
{
  int bx = blockIdx.x, b = blockIdx.y, tid = threadIdx.x;
  if (bx == N_){
    __shared__ float zs[H_];
    zs[tid] = z[b*H_ + tid];
    __syncthreads();
    float a0=0.f, a1=0.f;
    for (int k=0;k<H_;k++){
      float zv = zs[k];
      a0 += zv * Winit[(size_t)k*H_ + tid];
      a1 += zv * W1[(size_t)(2*H_ + k)*H_ + tid];
    }
    ws[H0_OFF + b*H_ + tid] = tanh_(a0 + binit[tid]);
    ws[ZC_OFF + b*H_ + tid] = a1 + b1[tid];
    if (b==0 && tid==0) out[LL_OUT] = 0.0f;
    return;
  }
  if (tid >= 64) return;
  int t = bx, lane = tid;
  uint32_t* wsu = (uint32_t*)ws;
  unsigned long long* ws64 = (unsigned long long*)ws;
  const float* row = tgt + ((size_t)(b*N_) + t)*N_;
  uint8_t* pl = ((uint8_t*)&wsu[PL_OFF]) + (size_t)(b*N_ + t)*N_;
  int cnt = 0;
  #pragma unroll
  for (int m=0;m<4;m++){
    float v = row[m*64 + lane];
    bool p = (v != 0.0f);
    unsigned long long bw = __ballot(p);
    if (lane == 0) ws64[TG64 + (size_t)(b*N_+t)*4 + m] = bw;
    if (p){
      int pos = cnt + (int)__popcll(bw & ((1ULL<<lane)-1ULL));
      pl[pos] = (uint8_t)(m*64 + lane);
    }
    cnt += (int)__popcll(bw);
  }
  if (lane == 0){
    wsu[PC_OFF + b*N_ + t] = (uint32_t)cnt;
    ws[DG_OFF + b*N_ + t] = 1.0f / fmaxf((float)cnt, 1.0f);
  }
}

// ---------- pre2: children lists (transpose of parent lists) ----------
__global__ void __launch_bounds__(64) k_pre2(float* ws)
{
  int j = blockIdx.x, b = blockIdx.y, lane = threadIdx.x;
  uint32_t* wsu = (uint32_t*)ws;
  unsigned long long* ws64 = (unsigned long long*)ws;
  uint8_t* cl = ((uint8_t*)&wsu[CL_OFF]) + (size_t)(b*N_ + j)*N_;
  int w = j >> 6; int sb = j & 63;
  int cnt = 0;
  #pragma unroll
  for (int m=0;m<4;m++){
    int t = m*64 + lane;
    unsigned long long rowm = ws64[TG64 + (size_t)(b*N_+t)*4 + w];
    bool p = ((rowm >> sb) & 1ULL) != 0ULL;
    unsigned long long bw = __ballot(p);
    if (p){
      int pos = cnt + (int)__popcll(bw & ((1ULL<<lane)-1ULL));
      cl[pos] = (uint8_t)t;
    }
    cnt += (int)__popcll(bw);
  }
  if (lane == 0) wsu[CC_OFF + b*N_ + j] = (uint32_t)cnt;
}

// ---------- pass 1 ----------
// 256 threads: tid<192 = (hh=tid>>4 hidden-in-slice... actually hh=tid/16? no:
// mapping: hh = tid>>4 in [0,12), kc = tid&15 in [0,16). Butterfly over the 16 kc
// lanes leaves full gate-col sums in every lane -> gates computed in-thread, no LDS
// relay; 2 barriers/step. Wave3: delayed PS scatter + ancestor rows.
__global__ void __launch_bounds__(256) k_pass1(const float* __restrict__ z,
    const float* __restrict__ Wih, const float* __restrict__ Whh,
    const float* __restrict__ bih_g, const float* __restrict__ bhh_g,
    float* ws)
{
  int bx = blockIdx.x;
  int b = bx & 7;
  if (b >= B_) return;
  int slice = bx >> 3;
  int tid = threadIdx.x;
  float* wsf = ws;
  uint32_t* wsu = (uint32_t*)ws;
  unsigned long long* ws64 = (unsigned long long*)ws;

  __shared__ __align__(16) float sruns[H_];
  __shared__ __align__(16) float sh[H_];
  __shared__ __align__(16) float sPS[N_*SC_];
  __shared__ __align__(16) float sdelta[2][SC_];
  __shared__ int sfast[16];
  __shared__ unsigned long long sAB[N_][4];
  __shared__ float sDG[N_], sTF1[N_], sTF2[N_];

  const int hh = tid >> 4;      // 0..11 for mv threads
  const int kc = tid & 15;
  const bool mv = tid < 192;

  // ---- XCD discovery + exchange (one-time; garbage-tolerant) ----
  uint32_t xcc = (uint32_t)__builtin_amdgcn_s_getreg((31u<<11) | 20u) & 15u;  // HW_REG_XCC_ID
  if (tid == 0)
    __hip_atomic_store(&wsu[XC_OFF + b*16 + slice], 0xC0DE0000u | xcc,
                       __ATOMIC_RELAXED, __HIP_MEMORY_SCOPE_AGENT);
  if (tid < 64){
    uint32_t v = 0; int ok;
    do {
      v = (tid < 16) ? __hip_atomic_load(&wsu[XC_OFF + b*16 + tid],
              __ATOMIC_RELAXED, __HIP_MEMORY_SCOPE_AGENT) : 0xC0DE0000u;
      ok = (int)((v >> 16) == 0xC0DEu);
    } while (!__all(ok));
    if (tid < 16) sfast[tid] = ((v & 0xFFu) == xcc) ? 1 : 0;
  }

  // ---- per-step scalar tables (deg^-1, tf1=bit(t-1) of row t, tf2=bit(t-2)) ----
  for (int i = tid; i < N_; i += 256){
    sDG[i] = wsf[DG_OFF + b*N_ + i];
    float f1 = 0.f, f2 = 0.f;
    if (i >= 1){
      unsigned long long w1 = ws64[TG64 + (size_t)(b*N_+i)*4 + ((i-1)>>6)];
      f1 = (float)((w1 >> ((i-1)&63)) & 1ULL);
    }
    if (i >= 2){
      unsigned long long w2 = ws64[TG64 + (size_t)(b*N_+i)*4 + ((i-2)>>6)];
      f2 = (float)((w2 >> ((i-2)&63)) & 1ULL);
    }
    sTF1[i] = f1; sTF2[i] = f2;
  }

  // ---- weights: thread (hh,kc) owns cols {g*192+slice*12+hh}, k in [kc*12,kc*12+12) ----
  float rwih[3][12], rwhh[3][12], rbih[3], rbhh[3], rghz[3];
  if (mv){
    #pragma unroll
    for (int g=0; g<3; g++){
      int col = g*H_ + slice*SH_ + hh;
      #pragma unroll
      for (int i=0;i<12;i++){
        rwih[g][i] = Wih[(size_t)(kc*12+i)*H3_ + col];
        rwhh[g][i] = Whh[(size_t)(kc*12+i)*H3_ + col];
      }
      rbih[g] = bih_g[col];
      rbhh[g] = bhh_g[col];
    }
    // ghz = z@W_hh + b_hh for the 3 cols (butterfly over kc)
    float a0=0.f,a1=0.f,a2=0.f;
    #pragma unroll
    for (int i=0;i<12;i++){
      float zv = z[b*H_ + kc*12 + i];
      a0 += zv*rwhh[0][i]; a1 += zv*rwhh[1][i]; a2 += zv*rwhh[2][i];
    }
    #pragma unroll
    for (int m=1;m<16;m<<=1){
      a0 += __shfl_xor(a0,m); a1 += __shfl_xor(a1,m); a2 += __shfl_xor(a2,m);
    }
    rghz[0]=a0+rbhh[0]; rghz[1]=a1+rbhh[1]; rghz[2]=a2+rbhh[2];
  }
  float zreg = mv ? z[b*H_ + slice*SH_ + hh] : 0.0f;
  for (int i = tid; i < N_*SC_; i += 256) sPS[i] = 0.0f;
  if (tid >= 192 && tid < 196) sAB[0][tid-192] = 0ULL;
  // publish S(0) (tag 1)
  if (mv && kc == 0){
    float v = wsf[H0_OFF + b*H_ + slice*SH_ + hh];
    int e = slice*SH_ + hh;
    pub_(&wsu[FSL_OFF + (unsigned)(b*N_)*384u + 2u*e],
         &wsu[SL_OFF  + (unsigned)(b*N_)*384u + 2u*e], v, 1u);
  }
  __syncthreads();

  const int fastf = mv ? sfast[tid/12] : 0;
  float rsum = 0.f;
  float qp0=0.f,qp1=0.f,qp2=0.f, dp0=0.f,dp1=0.f,dp2=0.f;

  for (int t=1; t<N_; t++){
    const uint32_t tagS = (uint32_t)t;
    const uint32_t tagH = (uint32_t)(t+1);
    // P1: poll S(t-1) element tid
    if (mv){
      float v = pollH_(&wsu[FSL_OFF + (unsigned)(b*N_+(t-1))*384u + 2u*(unsigned)tid],
                       &wsu[SL_OFF  + (unsigned)(b*N_+(t-1))*384u + 2u*(unsigned)tid],
                       fastf, tagS);
      rsum += v;
      sruns[tid] = rsum;
    }
    __syncthreads();   // B1
    float hp=0.f, a20=0.f, a21=0.f, a22=0.f;
    if (mv){
      float dginv = sDG[t], tf1 = sTF1[t], tf2 = sTF2[t];
      // mv1: q (3 cols) over k-chunk kc, butterfly -> full sums in all lanes
      float x[12];
      *(float4*)&x[0] = *(float4*)&sruns[kc*12];
      *(float4*)&x[4] = *(float4*)&sruns[kc*12+4];
      *(float4*)&x[8] = *(float4*)&sruns[kc*12+8];
      float q0=0.f,q1=0.f,q2=0.f;
      #pragma unroll
      for (int i=0;i<12;i++){
        q0 += x[i]*rwih[0][i]; q1 += x[i]*rwih[1][i]; q2 += x[i]*rwih[2][i];
      }
      #pragma unroll
      for (int m=1;m<16;m<<=1){
        q0 += __shfl_xor(q0,m); q1 += __shfl_xor(q1,m); q2 += __shfl_xor(q2,m);
      }
      float d0=q0-qp0, d1=q1-qp1, d2=q2-qp2;
      qp0=q0; qp1=q1; qp2=q2;
      if (kc == 0){
        sdelta[t&1][0*12+hh]=d0; sdelta[t&1][1*12+hh]=d1; sdelta[t&1][2*12+hh]=d2;
      }
      float pv0 = sPS[t*SC_ + 0*12 + hh];
      float pv1 = sPS[t*SC_ + 1*12 + hh];
      float pv2 = sPS[t*SC_ + 2*12 + hh];
      a20 = (pv0 + tf1*d0 + tf2*dp0)*dginv + rbih[0];
      a21 = (pv1 + tf1*d1 + tf2*dp1)*dginv + rbih[1];
      a22 = (pv2 + tf1*d2 + tf2*dp2)*dginv + rbih[2];
      dp0=d0; dp1=d1; dp2=d2;
      float invt = 1.0f/(float)t;
      float a10 = q0*invt + rbih[0];
      float a11 = q1*invt + rbih[1];
      float a12 = q2*invt + rbih[2];
      // gates1 in-thread
      float r = sigm_(a10 + rghz[0]);
      float u = sigm_(a11 + rghz[1]);
      float n = tanh_(a12 + r*rghz[2]);
      hp = (1.0f-u)*n + u*zreg;
      if (kc == 0){
        int e = slice*SH_ + hh;
        pub_(&wsu[FHL_OFF + (unsigned)(b*N_+t)*384u + 2u*e],
             &wsu[HL_OFF  + (unsigned)(b*N_+t)*384u + 2u*e], hp, tagH);
      }
      // P3: poll H(t) element tid
      float hv = pollH_(&wsu[FHL_OFF + (unsigned)(b*N_+t)*384u + 2u*(unsigned)tid],
                        &wsu[HL_OFF  + (unsigned)(b*N_+t)*384u + 2u*(unsigned)tid],
                        fastf, tagH);
      sh[tid] = hv;
    } else {
      int lane = tid - 192;
      if (lane < SC_){
        // delayed scatter: delta computed at step t-1 (= node t-2) -> children rows > t
        if (t >= 2){
          int node = t-2;
          int ccn = (int)wsu[CC_OFF + b*N_ + node];
          const uint8_t* cl = ((const uint8_t*)&wsu[CL_OFF]) + (size_t)(b*N_ + node)*N_;
          float dd = sdelta[(t-1)&1][lane];
          for (int i=0;i<ccn;i++){
            int tc = cl[i];
            if (tc > t) sPS[tc*SC_ + lane] += dd;
          }
        }
      } else if (lane < SC_+4){
        // ancestor row t (private per block; slice 0 exports)
        int w = lane - SC_;
        int npt = (int)wsu[PC_OFF + b*N_ + t];
        const uint8_t* pb = ((const uint8_t*)&wsu[PL_OFF]) + (size_t)(b*N_ + t)*N_;
        unsigned long long acc = 0ULL;
        for (int i=0;i<npt;i++) acc |= sAB[pb[i]][w];
        if (slice == 0) ws64[AN64 + (size_t)(b*N_+t)*4 + w] = acc;
        sAB[t][w] = acc | ws64[TG64 + (size_t)(b*N_+t)*4 + w];
      }
    }
    __syncthreads();   // B2
    if (mv){
      // mv2: gh2 (3 cols) from full h_prov
      float x[12];
      *(float4*)&x[0] = *(float4*)&sh[kc*12];
      *(float4*)&x[4] = *(float4*)&sh[kc*12+4];
      *(float4*)&x[8] = *(float4*)&sh[kc*12+8];
      float y0=0.f,y1=0.f,y2=0.f;
      #pragma unroll
      for (int i=0;i<12;i++){
        y0 += x[i]*rwhh[0][i]; y1 += x[i]*rwhh[1][i]; y2 += x[i]*rwhh[2][i];
      }
      #pragma unroll
      for (int m=1;m<16;m<<=1){
        y0 += __shfl_xor(y0,m); y1 += __shfl_xor(y1,m); y2 += __shfl_xor(y2,m);
      }
      // gates2 in-thread
      float r2 = sigm_(a20 + y0 + rbhh[0]);
      float u2 = sigm_(a21 + y1 + rbhh[1]);
      float n2 = tanh_(a22 + r2*(y2 + rbhh[2]));
      float hn = (1.0f-u2)*n2 + u2*hp;
      if (kc == 0){
        int e = slice*SH_ + hh;
        pub_(&wsu[FSL_OFF + (unsigned)(b*N_+t)*384u + 2u*e],
             &wsu[SL_OFF  + (unsigned)(b*N_+t)*384u + 2u*e], hn, tagH);
      }
    }
  }
}

// ---------- pass 2a: G^T = (S@W1b)^T, C = Hprov@W1a + zc, NF = S@Wf + bf ----------
__global__ void k_p2a(const float* __restrict__ W1, const float* __restrict__ Wf,
    const float* __restrict__ bf, float* ws, float* out)
{
  int j = blockIdx.x, b = blockIdx.y, tid = threadIdx.x;
  __shared__ float srow[H_], hrow[H_];
  __shared__ float nfp[3][F_];
  srow[tid] = ws[SL_OFF + (unsigned)(b*N_+j)*384u + 2u*tid];
  hrow[tid] = ws[HL_OFF + (unsigned)(b*N_+j)*384u + 2u*tid];   // garbage for j=0, C[0] unused
  __syncthreads();
  float accG = 0.f, accC = 0.f;
  for (int k=0;k<H_;k++){
    float sv = srow[k], hv = hrow[k];
    accG += sv * W1[(size_t)(H_+k)*H_ + tid];
    accC += hv * W1[(size_t)k*H_ + tid];
  }
  ws[G_OFF + ((size_t)b*H_ + tid)*N_ + j] = accG;    // transposed store
  ws[C_OFF + (size_t)(b*N_+j)*H_ + tid] = accC + ws[ZC_OFF + b*H_ + tid];
  int f = tid & 63, kp = tid >> 6;
  float a = 0.f;
  for (int i=0;i<64;i++){ int k = kp*64 + i; a += srow[k]*Wf[(size_t)k*F_ + f]; }
  nfp[kp][f] = a;
  __syncthreads();
  if (tid < F_) out[NF_OUT + (size_t)(b*N_+j)*F_ + tid] = nfp[0][tid]+nfp[1][tid]+nfp[2][tid] + bf[tid];
}

// ---------- pass 2b: log-likelihood, lane-per-candidate-parent ----------
__global__ void __launch_bounds__(256) k_p2b(const float* __restrict__ W2,
    const float* __restrict__ b2p, float* ws, float* out)
{
  int t = blockIdx.x + 1, b = blockIdx.y;
  int tid = threadIdx.x; int lane = tid & 63; int wv = tid >> 6;
  __shared__ float cv[H_], w2s[H_];
  __shared__ float wsum[4];
  unsigned long long* ws64 = (unsigned long long*)ws;
  if (tid < H_){
    cv[tid] = ws[C_OFF + (size_t)(b*N_+t)*H_ + tid];
    w2s[tid] = W2[tid];
  }
  __syncthreads();
  float acc = 0.f;
  if (tid < t){
    const float* GT = ws + G_OFF + (size_t)b*H_*N_;
    float a = 0.f;
    for (int k=0;k<H_;k++) a += fmaxf(cv[k] + GT[(size_t)k*N_ + tid], 0.f) * w2s[k];
    float logit = a + b2p[0];
    float pp = 1.0f/(1.0f+__expf(-logit));
    unsigned long long an = ws64[AN64 + (size_t)(b*N_+t)*4 + (tid>>6)];
    unsigned long long tg = ws64[TG64 + (size_t)(b*N_+t)*4 + (tid>>6)];
    float anc = (float)((an >> (tid&63)) & 1ULL);
    pp = pp * (1.0f - anc);
    pp = fminf(fmaxf(pp, 1e-6f), 1.0f - 1e-6f);
    int tgb = (int)((tg >> (tid&63)) & 1ULL);
    acc = tgb ? logf(pp) : log1pf(-pp);
  }
  #pragma unroll
  for (int m=32;m>=1;m>>=1) acc += __shfl_xor(acc, m);
  if (lane == 0) wsum[wv] = acc;
  __syncthreads();
  if (tid == 0) atomicAdd(out + LL_OUT, wsum[0]+wsum[1]+wsum[2]+wsum[3]);
}

extern "C" void kernel_launch(void* const* d_in, const int* in_sizes, int n_in,
                              void* d_out, int out_size, void* d_ws, size_t ws_size,
                              hipStream_t stream) {
  (void)in_sizes; (void)n_in; (void)out_size; (void)ws_size;
  const float* z     = (const float*)d_in[0];
  const float* tgt   = (const float*)d_in[1];
  const float* Winit = (const float*)d_in[2];
  const float* binit = (const float*)d_in[3];
  const float* Wih   = (const float*)d_in[4];
  const float* Whh   = (const float*)d_in[5];
  const float* bih   = (const float*)d_in[6];
  const float* bhh   = (const float*)d_in[7];
  const float* W1    = (const float*)d_in[8];
  const float* b1    = (const float*)d_in[9];
  const float* W2    = (const float*)d_in[10];
  const float* b2    = (const float*)d_in[11];
  const float* Wf    = (const float*)d_in[12];
  const float* bf    = (const float*)d_in[13];
  float* out = (float*)d_out;
  float* ws  = (float*)d_ws;

  hipMemcpyAsync(d_out, d_in[1], (size_t)B_*N_*N_*sizeof(float), hipMemcpyDeviceToDevice, stream);

  k_pre1<<<dim3(N_+1, B_), dim3(192), 0, stream>>>(z, Winit, binit, W1, b1, tgt, ws, out);
  k_pre2<<<dim3(N_, B_), dim3(64), 0, stream>>>(ws);
  k_pass1<<<dim3(128), dim3(256), 0, stream>>>(z, Wih, Whh, bih, bhh, ws);
  k_p2a<<<dim3(N_, B_), dim3(H_), 0, stream>>>(W1, Wf, bf, ws, out);
  k_p2b<<<dim3(N_-1, B_), dim3(256), 0, stream>>>(W2, b2, ws, out);
}